// Round 8
// baseline (1201.136 us; speedup 1.0000x reference)
//
#include <hip/hip_runtime.h>

#define TT 96
#define FF 32
#define HH 128
#define G4 512
#define LOG2E 1.4426950408889634f

typedef _Float16 h2 __attribute__((ext_vector_type(2)));

__device__ __forceinline__ float fexp2(float x){ return __builtin_amdgcn_exp2f(x); }
__device__ __forceinline__ float frcp(float x){ return __builtin_amdgcn_rcpf(x); }
__device__ __forceinline__ float fsigmoid(float x){ return frcp(1.0f + fexp2(-LOG2E*x)); }
__device__ __forceinline__ float ftanh(float x){
    float u = fexp2(2.0f*LOG2E*x);
    return 1.0f - 2.0f*frcp(1.0f + u);
}
__device__ __forceinline__ h2 pk(float a, float b){
    h2 r; r.x = (_Float16)a; r.y = (_Float16)b; return r;
}
__device__ __forceinline__ unsigned pku(float a, float b){
    return __builtin_bit_cast(unsigned, pk(a, b));
}
__device__ __forceinline__ h2 u2h(unsigned v){ return __builtin_bit_cast(h2, v); }
__device__ __forceinline__ float fdot2(h2 a, h2 b, float c){
#if __has_builtin(__builtin_amdgcn_fdot2)
    return __builtin_amdgcn_fdot2(a, b, c, false);
#else
    return c + (float)a.x*(float)b.x + (float)a.y*(float)b.y;
#endif
}

// ---------------------------------------------------------------------------
// k_prep: G = fc_w[0:128]@dec_k packed f16 pairs, [g][u] uint4 layout
// (g = group of 8 k's). gy = fc_w[128]@dec_k; gb = fc_b@dec_k + dec_b.
// ---------------------------------------------------------------------------
__global__ __launch_bounds__(256) void k_prep(const float* __restrict__ fc_w,
                                              const float* __restrict__ fc_b,
                                              const float* __restrict__ dec_k,
                                              const float* __restrict__ dec_b,
                                              h2* __restrict__ Gp,
                                              float* __restrict__ gy,
                                              float* __restrict__ gb){
    int blk = blockIdx.x, tid = threadIdx.x;
    int u0 = tid, u1 = tid + 256;
    if (blk < 16){
        float a0[8], a1[8];
        #pragma unroll
        for (int r = 0; r < 8; ++r){ a0[r] = 0.f; a1[r] = 0.f; }
        for (int m = 0; m < 128; ++m){
            float d0 = dec_k[m*G4 + u0], d1 = dec_k[m*G4 + u1];
            #pragma unroll
            for (int r = 0; r < 8; ++r){
                float w = fc_w[(blk*8 + r)*HH + m];
                a0[r] += w * d0; a1[r] += w * d1;
            }
        }
        #pragma unroll
        for (int c = 0; c < 4; ++c){
            Gp[(blk*G4 + u0)*4 + c] = pk(a0[2*c], a0[2*c+1]);
            Gp[(blk*G4 + u1)*4 + c] = pk(a1[2*c], a1[2*c+1]);
        }
    } else if (blk == 16){
        float a0 = 0.f, a1 = 0.f;
        for (int m = 0; m < 128; ++m){
            float w = fc_w[128*HH + m];
            a0 += w * dec_k[m*G4 + u0]; a1 += w * dec_k[m*G4 + u1];
        }
        gy[u0] = a0; gy[u1] = a1;
    } else {
        float a0 = 0.f, a1 = 0.f;
        for (int m = 0; m < 128; ++m){
            float w = fc_b[m];
            a0 += w * dec_k[m*G4 + u0]; a1 += w * dec_k[m*G4 + u1];
        }
        gb[u0] = a0 + dec_b[u0]; gb[u1] = a1 + dec_b[u1];
    }
}

// ---------------------------------------------------------------------------
// k_enc: 1024 threads. Round-8: attention-proj and e-phase reduced via
// in-wave shuffles (4 barriers/step, was 6). x_tilde built locally from PF.
// z keeps lane-consecutive u mapping (KLH4 bank-freedom) + PPZ combine.
// ---------------------------------------------------------------------------
__global__ __launch_bounds__(1024, 1) void k_enc(const float* __restrict__ inputs,
                                                 const float* __restrict__ enc_k,
                                                 const float* __restrict__ enc_r,
                                                 const float* __restrict__ enc_b,
                                                 const float* __restrict__ ae_w1,
                                                 const float* __restrict__ ae_b1,
                                                 const float* __restrict__ ae_w2,
                                                 float* __restrict__ ws_xenc){
    extern __shared__ float lds[];
    uint4* KLH4 = (uint4*)lds;            // [4][512] uint4 = 8192 floats
    float* XPJT = lds + 8192;             // [128][33] = 4224
    float* XIN  = lds + 12416;            // [96][32]  = 3072
    float* CST  = lds + 15488;            // 128 (c state fp32)
    float* PE   = lds + 15616;            // 128
    float* W2E  = lds + 15744;            // 128
    float* PPZ  = lds + 15872;            // 1024
    h2*    HSP  = (h2*)(lds + 16896);     // 128 h2: h-pairs 0..63, s-pairs 64..127
    float* PF   = lds + 17024;            // 32 (exp(e) per f)
    float* WS2  = lds + 17056;            // 16 wave exp-partials
    // total 17072 floats = 68288 B

    const int b = blockIdx.x, tid = threadIdx.x;
    const int jA = tid >> 3, qA = tid & 7;      // attention shuffle mapping
    const int u2 = tid & 511, hf2 = tid >> 9;   // z mapping (lane-consecutive)
    const float* xin_g = inputs + b*TT*FF;

    for (int i = tid; i < TT*FF; i += 1024) XIN[i] = xin_g[i];
    for (int i = tid; i < 2048; i += 1024){     // enc_k -> f16 LDS
        int f8 = i >> 9, uu = i & 511;
        uint4 qv;
        qv.x = pku(enc_k[(f8*8+0)*G4+uu], enc_k[(f8*8+1)*G4+uu]);
        qv.y = pku(enc_k[(f8*8+2)*G4+uu], enc_k[(f8*8+3)*G4+uu]);
        qv.z = pku(enc_k[(f8*8+4)*G4+uu], enc_k[(f8*8+5)*G4+uu]);
        qv.w = pku(enc_k[(f8*8+6)*G4+uu], enc_k[(f8*8+7)*G4+uu]);
        KLH4[i] = qv;
    }
    if (tid < 128){ W2E[tid] = ae_w2[tid]; HSP[tid] = pk(0.f, 0.f); CST[tid] = 0.f; }

    h2 wa_p[16], rp_e[32];
    #pragma unroll
    for (int i = 0; i < 16; ++i)
        wa_p[i] = pk(ae_w1[(qA*32 + 2*i)*HH + jA], ae_w1[(qA*32 + 2*i+1)*HH + jA]);
    #pragma unroll
    for (int i = 0; i < 32; ++i)
        rp_e[i] = pk(enc_r[(hf2*64 + 2*i)*G4 + u2], enc_r[(hf2*64 + 2*i+1)*G4 + u2]);
    const float ebr  = (hf2 == 0) ? enc_b[u2] : 0.f;
    const float ab1r = ae_b1[jA];
    __syncthreads();

    {   // XPJT[j][f] = sum_t x[t][f]*ae_w1[(256+t)*128+j]  (time-invariant)
        int j = tid & 127, fh = tid >> 7;
        float a0=0.f, a1=0.f, a2=0.f, a3=0.f;
        for (int t = 0; t < TT; ++t){
            float w = ae_w1[(256 + t)*HH + j];
            const float* xr = &XIN[t*FF + fh*4];
            a0 += xr[0]*w; a1 += xr[1]*w; a2 += xr[2]*w; a3 += xr[3]*w;
        }
        XPJT[j*33 + fh*4 + 0] = a0;
        XPJT[j*33 + fh*4 + 1] = a1;
        XPJT[j*33 + fh*4 + 2] = a2;
        XPJT[j*33 + fh*4 + 3] = a3;
    }
    __syncthreads();

    const uint4* HSP4 = (const uint4*)HSP;

    for (int t = 0; t < TT; ++t){
        // Phase1: att-proj partial (k-range qA*32..+31 of [h;s]) -> shuffle -> PE
        float z;
        {
            float a0 = 0.f, a1 = 0.f;
            #pragma unroll
            for (int i4 = 0; i4 < 4; ++i4){
                uint4 hq = HSP4[qA*4 + i4];        // same-address broadcast
                a0 = fdot2(u2h(hq.x), wa_p[i4*4+0], a0);
                a1 = fdot2(u2h(hq.y), wa_p[i4*4+1], a1);
                a0 = fdot2(u2h(hq.z), wa_p[i4*4+2], a0);
                a1 = fdot2(u2h(hq.w), wa_p[i4*4+3], a1);
            }
            float aa = a0 + a1;
            aa += __shfl_xor(aa, 1);
            aa += __shfl_xor(aa, 2);
            aa += __shfl_xor(aa, 4);
            // z-partial: h@enc_r (old mapping, broadcast reads)
            z = ebr;
            float z2 = 0.f;
            #pragma unroll
            for (int i4 = 0; i4 < 8; ++i4){
                uint4 hq = HSP4[hf2*8 + i4];
                z  = fdot2(u2h(hq.x), rp_e[i4*4+0], z);
                z2 = fdot2(u2h(hq.y), rp_e[i4*4+1], z2);
                z  = fdot2(u2h(hq.z), rp_e[i4*4+2], z);
                z2 = fdot2(u2h(hq.w), rp_e[i4*4+3], z2);
            }
            z += z2;
            if (qA == 0) PE[jA] = aa + ab1r;
        }
        __syncthreads();  // B1
        // Phase2: e[f] via 32-lane shuffle; PF = exp(e); WS2 wave partials
        {
            int f = tid >> 5, jl = tid & 31;
            float acc = 0.f;
            #pragma unroll
            for (int i = 0; i < 4; ++i){
                int jx = jl + 32*i;
                acc += ftanh(PE[jx] + XPJT[jx*33 + f]) * W2E[jx];
            }
            acc += __shfl_xor(acc, 1);
            acc += __shfl_xor(acc, 2);
            acc += __shfl_xor(acc, 4);
            acc += __shfl_xor(acc, 8);
            acc += __shfl_xor(acc, 16);
            float p = 0.f;
            if (jl == 0){ p = fexp2(acc * LOG2E); PF[f] = p; }
            float pw = p + __shfl_xor(p, 32);
            if ((tid & 63) == 0) WS2[tid >> 6] = pw;
        }
        __syncthreads();  // B2
        // Phase3: x_tilde local (PF broadcasts) + z finish -> PPZ
        {
            float ssum = 0.f;
            #pragma unroll
            for (int w = 0; w < 16; ++w) ssum += WS2[w];
            float inv = frcp(ssum);
            float z2 = 0.f;
            #pragma unroll
            for (int c = 0; c < 2; ++c){
                int f8 = hf2*2 + c;
                float4 p0 = *(const float4*)&PF[f8*8];
                float4 p1 = *(const float4*)&PF[f8*8 + 4];
                float4 x0 = *(const float4*)&XIN[t*FF + f8*8];
                float4 x1 = *(const float4*)&XIN[t*FF + f8*8 + 4];
                h2 t0 = pk(p0.x*x0.x*inv, p0.y*x0.y*inv);
                h2 t1 = pk(p0.z*x0.z*inv, p0.w*x0.w*inv);
                h2 t2 = pk(p1.x*x1.x*inv, p1.y*x1.y*inv);
                h2 t3 = pk(p1.z*x1.z*inv, p1.w*x1.w*inv);
                uint4 kq = KLH4[f8*512 + u2];
                z  = fdot2(u2h(kq.x), t0, z);
                z2 = fdot2(u2h(kq.y), t1, z2);
                z  = fdot2(u2h(kq.z), t2, z);
                z2 = fdot2(u2h(kq.w), t3, z2);
            }
            PPZ[hf2*512 + u2] = z + z2;
        }
        __syncthreads();  // B3
        // Phase4: gates + state
        if (tid < 128){
            int j = tid;
            float zi = PPZ[j]       + PPZ[512 + j];
            float zf = PPZ[128 + j] + PPZ[640 + j];
            float zg = PPZ[256 + j] + PPZ[768 + j];
            float zo = PPZ[384 + j] + PPZ[896 + j];
            float cn = fsigmoid(zf) * CST[j] + fsigmoid(zi) * ftanh(zg);
            float hn = fsigmoid(zo) * ftanh(cn);
            CST[j] = cn;
            ws_xenc[(b*TT + t)*HH + j] = hn;
            float hn2 = __shfl_xor(hn, 1);
            float cn2 = __shfl_xor(cn, 1);
            if (!(j & 1)){
                HSP[j >> 1]        = pk(hn, hn2);
                HSP[64 + (j >> 1)] = pk(cn, cn2);
            }
        }
        __syncthreads();  // B4
    }
}

// ---------------------------------------------------------------------------
// k_xept: xeptT[b][j][t] = sum_k x_enc[b][t][k] * ad_w1[(256+k)*128 + j]
// ---------------------------------------------------------------------------
__global__ __launch_bounds__(256) void k_xept(const float* __restrict__ ws_xenc,
                                              const float* __restrict__ ad_w1,
                                              float* __restrict__ ws_xept){
    int b = blockIdx.x, q = blockIdx.y, tid = threadIdx.x;
    int j = tid & 127, th = tid >> 7;
    const float* xb = ws_xenc + b*TT*HH;
    float acc[12];
    #pragma unroll
    for (int i = 0; i < 12; ++i) acc[i] = 0.f;
    for (int k = 0; k < 128; ++k){
        float w = ad_w1[(256 + k)*HH + j];
        #pragma unroll
        for (int i = 0; i < 12; ++i){
            int tp = q*24 + th*12 + i;
            acc[i] += xb[tp*HH + k] * w;
        }
    }
    #pragma unroll
    for (int i = 0; i < 12; ++i){
        int tp = q*24 + th*12 + i;
        ws_xept[(b*HH + j)*TT + tp] = acc[i];
    }
}

// ---------------------------------------------------------------------------
// k_dec: 1024 threads. Round-8: 5 barriers/step (was 8). Shuffle-reduced
// attention-proj; EP stores exp(e) (beta rebuilt locally); gate fusion via
// 8-lane shuffles (u = (q>>1)*128+j mapping; z-path reads are broadcasts/global).
// ---------------------------------------------------------------------------
__global__ __launch_bounds__(1024, 1) void k_dec(const float* __restrict__ inputs,
                                                 const float* __restrict__ dec_r,
                                                 const float* __restrict__ ad_w1,
                                                 const float* __restrict__ ad_b1,
                                                 const float* __restrict__ ad_w2,
                                                 const float* __restrict__ ff_w,
                                                 const float* __restrict__ ff_b,
                                                 const h2* __restrict__ Gp,
                                                 const float* __restrict__ gy,
                                                 const float* __restrict__ gb,
                                                 const float* __restrict__ ws_xenc,
                                                 const float* __restrict__ ws_xept,
                                                 float* __restrict__ out){
    extern __shared__ float lds[];
    uint4* XE4 = (uint4*)lds;             // [12][128] uint4 = 6144 floats
    float* XPT = lds + 6144;              // [128][100] = 12800 (stride 100: <=2-way banks)
    float* PP  = lds + 18944;             // 1024
    float* DST = lds + 19968;             // 256: d, c
    float* APJ = lds + 20224;             // 128
    float* CTX = lds + 20352;             // 128
    float* W2L = lds + 20480;             // 128
    h2*    DCP = (h2*)(lds + 20608);      // 128 h2: d-pairs 0..63, c-pairs 64..127
    h2*    CXP = (h2*)(lds + 20736);      // 64 h2: ctx pairs
    float* EP  = lds + 20800;             // 128 (96 used): exp(e[t'])
    float* WS  = lds + 20928;             // 16 wave exp-partials
    float* YV  = lds + 20944;             // 96 y_prev
    // total 21040 floats = 84160 B

    const int b = blockIdx.x, tid = threadIdx.x;
    const int jA = tid >> 3, qA = tid & 7;      // unit row / partial index
    const int hf = qA & 1;                      // k-half
    const int u  = (qA >> 1)*128 + jA;          // gate-z column

    {   // x_enc -> LDS f16 t-pairs
        const float* xe_g = ws_xenc + b*TT*HH;
        for (int i = tid; i < 12*HH; i += 1024){
            int t8 = i >> 7, k = i & 127;
            uint4 qq;
            qq.x = pku(xe_g[(t8*8 + 0)*HH + k], xe_g[(t8*8 + 1)*HH + k]);
            qq.y = pku(xe_g[(t8*8 + 2)*HH + k], xe_g[(t8*8 + 3)*HH + k]);
            qq.z = pku(xe_g[(t8*8 + 4)*HH + k], xe_g[(t8*8 + 5)*HH + k]);
            qq.w = pku(xe_g[(t8*8 + 6)*HH + k], xe_g[(t8*8 + 7)*HH + k]);
            XE4[i] = qq;
        }
    }
    {   // xept -> LDS, stride 96 -> 100
        const float* src = ws_xept + b*HH*TT + jA*96 + qA*12;
        float* dst = &XPT[jA*100 + qA*12];
        #pragma unroll
        for (int i = 0; i < 12; ++i) dst[i] = src[i];
    }
    if (tid < TT) YV[tid] = inputs[b*TT*FF + tid*FF + (FF-1)];
    if (tid < 128){ W2L[tid] = ad_w2[tid]; DCP[tid] = pk(0.f, 0.f); }
    if (tid < 256) DST[tid] = 0.f;

    h2 rp[32], wp[16];
    #pragma unroll
    for (int i = 0; i < 32; ++i)
        rp[i] = pk(dec_r[(hf*64 + 2*i)*G4 + u], dec_r[(hf*64 + 2*i+1)*G4 + u]);
    #pragma unroll
    for (int i = 0; i < 16; ++i)
        wp[i] = pk(ad_w1[(qA*32 + 2*i)*HH + jA], ad_w1[(qA*32 + 2*i+1)*HH + jA]);
    const float gbr = gb[u], gyr = gy[u];
    const float ab1r = ad_b1[jA];
    __syncthreads();

    const uint4* GQ   = (const uint4*)Gp;
    const uint4* DCP4 = (const uint4*)DCP;
    const uint4* CXP4 = (const uint4*)CXP;

    for (int t = 0; t < TT; ++t){
        float z;
        // Phase1: att-proj partial -> shuffle -> APJ; z-partial d@dec_r
        {
            float a0 = 0.f, a1 = 0.f;
            #pragma unroll
            for (int i4 = 0; i4 < 4; ++i4){
                uint4 dq = DCP4[qA*4 + i4];        // broadcast
                a0 = fdot2(u2h(dq.x), wp[i4*4+0], a0);
                a1 = fdot2(u2h(dq.y), wp[i4*4+1], a1);
                a0 = fdot2(u2h(dq.z), wp[i4*4+2], a0);
                a1 = fdot2(u2h(dq.w), wp[i4*4+3], a1);
            }
            float aa = a0 + a1;
            aa += __shfl_xor(aa, 1);
            aa += __shfl_xor(aa, 2);
            aa += __shfl_xor(aa, 4);
            z = (hf == 0) ? (gbr + YV[t]*gyr) : 0.f;
            float z2 = 0.f;
            #pragma unroll
            for (int i4 = 0; i4 < 8; ++i4){
                uint4 dq = DCP4[hf*8 + i4];        // broadcast
                z  = fdot2(u2h(dq.x), rp[i4*4+0], z);
                z2 = fdot2(u2h(dq.y), rp[i4*4+1], z2);
                z  = fdot2(u2h(dq.z), rp[i4*4+2], z);
                z2 = fdot2(u2h(dq.w), rp[i4*4+3], z2);
            }
            z += z2;
            if (qA == 0) APJ[jA] = aa + ab1r;
        }
        __syncthreads();  // B1
        // Phase2: e[t'] via 8-lane shuffle; EP = exp(e); WS wave partials
        {
            int tp = jA, jg = qA;                  // tp 0..127 (96 valid)
            float acc = 0.f;
            if (tp < TT){
                #pragma unroll
                for (int jj = 0; jj < 16; ++jj){
                    int jx = jg + 8*jj;
                    acc += ftanh(APJ[jx] + XPT[jx*100 + tp]) * W2L[jx];
                }
            }
            acc += __shfl_xor(acc, 1);
            acc += __shfl_xor(acc, 2);
            acc += __shfl_xor(acc, 4);
            float p = 0.f;
            if (jg == 0 && tp < TT){ p = fexp2(acc * LOG2E); EP[tp] = p; }
            float pw = p;
            pw += __shfl_xor(pw, 8);
            pw += __shfl_xor(pw, 16);
            pw += __shfl_xor(pw, 32);
            if ((tid & 63) == 0) WS[tid >> 6] = pw;
        }
        __syncthreads();  // B2
        // Phase3: ctx_un partials with locally rebuilt beta (EP broadcasts)
        {
            int k = tid & 127, th = tid >> 7;
            int t8a = (th < 4) ? th*2 : th + 4;
            int cnt = (th < 4) ? 2 : 1;
            float a = 0.f;
            for (int i = 0; i < cnt; ++i){
                int t8 = t8a + i;
                float4 e0 = *(const float4*)&EP[t8*8];
                float4 e1 = *(const float4*)&EP[t8*8 + 4];
                h2 b0 = pk(e0.x, e0.y), b1 = pk(e0.z, e0.w);
                h2 b2 = pk(e1.x, e1.y), b3 = pk(e1.z, e1.w);
                uint4 xq = XE4[t8*HH + k];
                a = fdot2(u2h(xq.x), b0, a);
                a = fdot2(u2h(xq.y), b1, a);
                a = fdot2(u2h(xq.z), b2, a);
                a = fdot2(u2h(xq.w), b3, a);
            }
            PP[tid] = a;
        }
        __syncthreads();  // B3
        // Phase4: ctx reduce + normalize (redundant 1/sum from WS) + CXP
        if (tid < 128){
            float ssum = 0.f;
            #pragma unroll
            for (int w = 0; w < 16; ++w) ssum += WS[w];
            float inv = frcp(ssum);
            float s = 0.f;
            #pragma unroll
            for (int g = 0; g < 8; ++g) s += PP[tid + 128*g];
            float cv = s * inv;
            CTX[tid] = cv;
            float cv2 = __shfl_xor(cv, 1);
            if (!(tid & 1)) CXP[tid >> 1] = pk(cv, cv2);
        }
        __syncthreads();  // B4
        // Phase5: z += ctx@G (global G, broadcast CXP) + fused gates
        {
            float z2 = 0.f;
            #pragma unroll
            for (int gi = 0; gi < 8; ++gi){
                int g = hf*8 + gi;
                uint4 gq = GQ[g*G4 + u];
                uint4 cc = CXP4[g];                // broadcast
                z  = fdot2(u2h(gq.x), u2h(cc.x), z);
                z2 = fdot2(u2h(gq.y), u2h(cc.y), z2);
                z  = fdot2(u2h(gq.z), u2h(cc.z), z);
                z2 = fdot2(u2h(gq.w), u2h(cc.w), z2);
            }
            z += z2;
            // 8-lane gate combine: q pairs (hf) then gate slots
            float s1  = z + __shfl_xor(z, 1);
            float zf_ = __shfl_xor(s1, 2);
            float zg_ = __shfl_xor(s1, 4);
            float zo_ = __shfl_xor(s1, 6);
            if (qA == 0){
                float cn = fsigmoid(zf_) * DST[128 + jA] + fsigmoid(s1) * ftanh(zg_);
                float hn = fsigmoid(zo_) * ftanh(cn);
                DST[128 + jA] = cn;
                DST[jA] = hn;
                float hn2 = __shfl_xor(hn, 8);
                float cn2 = __shfl_xor(cn, 8);
                if (!(jA & 1)){
                    DCP[jA >> 1]        = pk(hn, hn2);
                    DCP[64 + (jA >> 1)] = pk(cn, cn2);
                }
            }
        }
        __syncthreads();  // B5
    }

    // output: y_pred = [d_n, ctx] @ ff_w + ff_b (fp32)
    {
        int jp = tid & 31, sg = tid >> 5;
        float a = 0.f;
        #pragma unroll
        for (int kk = 0; kk < 8; ++kk){
            int k = sg*8 + kk;
            float val = (k < 128) ? DST[k] : CTX[k - 128];
            a += val * ff_w[k*FF + jp];
        }
        PP[sg*32 + jp] = a;
    }
    __syncthreads();
    if (tid < 32){
        float o = ff_b[tid];
        #pragma unroll
        for (int s = 0; s < 32; ++s) o += PP[s*32 + tid];
        out[b*FF + tid] = o;
    }
}

// ---------------------------------------------------------------------------
extern "C" void kernel_launch(void* const* d_in, const int* in_sizes, int n_in,
                              void* d_out, int out_size, void* d_ws, size_t ws_size,
                              hipStream_t stream) {
    const float* inputs = (const float*)d_in[0];
    const float* enc_k  = (const float*)d_in[1];
    const float* enc_r  = (const float*)d_in[2];
    const float* enc_b  = (const float*)d_in[3];
    const float* ae_w1  = (const float*)d_in[4];
    const float* ae_b1  = (const float*)d_in[5];
    const float* ae_w2  = (const float*)d_in[6];
    // d_in[7] = ae_b2 (softmax-invariant, unused)
    const float* dec_k  = (const float*)d_in[8];
    const float* dec_r  = (const float*)d_in[9];
    const float* dec_b  = (const float*)d_in[10];
    const float* ad_w1  = (const float*)d_in[11];
    const float* ad_b1  = (const float*)d_in[12];
    const float* ad_w2  = (const float*)d_in[13];
    // d_in[14] = ad_b2 (softmax-invariant, unused)
    const float* fc_w   = (const float*)d_in[15];
    const float* fc_b   = (const float*)d_in[16];
    const float* ff_w   = (const float*)d_in[17];
    const float* ff_b   = (const float*)d_in[18];

    float* ws      = (float*)d_ws;
    float* ws_xenc = ws;                     // 64*96*128 floats
    float* ws_xept = ws + 786432;            // 64*128*96 floats
    h2*    Gp      = (h2*)(ws + 1572864);    // 32768 h2 (128 KB)
    float* gy      = ws + 1605632;           // 512
    float* gb      = ws + 1606144;           // 512

    hipFuncSetAttribute((const void*)k_enc, hipFuncAttributeMaxDynamicSharedMemorySize, 68288);
    hipFuncSetAttribute((const void*)k_dec, hipFuncAttributeMaxDynamicSharedMemorySize, 84160);

    k_prep<<<18, 256, 0, stream>>>(fc_w, fc_b, dec_k, dec_b, Gp, gy, gb);
    k_enc<<<64, 1024, 68288, stream>>>(inputs, enc_k, enc_r, enc_b, ae_w1, ae_b1, ae_w2, ws_xenc);
    k_xept<<<dim3(64, 4), 256, 0, stream>>>(ws_xenc, ad_w1, ws_xept);
    k_dec<<<64, 1024, 84160, stream>>>(inputs, dec_r, ad_w1, ad_b1, ad_w2, ff_w, ff_b,
                                       Gp, gy, gb, ws_xenc, ws_xept, (float*)d_out);
}

// Round 9
// 1178.961 us; speedup vs baseline: 1.0188x; 1.0188x over previous
//
#include <hip/hip_runtime.h>

#define TT 96
#define FF 32
#define HH 128
#define G4 512
#define LOG2E 1.4426950408889634f

typedef _Float16 h2 __attribute__((ext_vector_type(2)));

__device__ __forceinline__ float fexp2(float x){ return __builtin_amdgcn_exp2f(x); }
__device__ __forceinline__ float frcp(float x){ return __builtin_amdgcn_rcpf(x); }
__device__ __forceinline__ float fsigmoid(float x){ return frcp(1.0f + fexp2(-LOG2E*x)); }
__device__ __forceinline__ float ftanh(float x){
    float u = fexp2(2.0f*LOG2E*x);
    return 1.0f - 2.0f*frcp(1.0f + u);
}
__device__ __forceinline__ h2 pk(float a, float b){
    h2 r; r.x = (_Float16)a; r.y = (_Float16)b; return r;
}
__device__ __forceinline__ unsigned pku(float a, float b){
    return __builtin_bit_cast(unsigned, pk(a, b));
}
__device__ __forceinline__ h2 u2h(unsigned v){ return __builtin_bit_cast(h2, v); }
__device__ __forceinline__ float fdot2(h2 a, h2 b, float c){
#if __has_builtin(__builtin_amdgcn_fdot2)
    return __builtin_amdgcn_fdot2(a, b, c, false);
#else
    return c + (float)a.x*(float)b.x + (float)a.y*(float)b.y;
#endif
}

// ---------------------------------------------------------------------------
// k_prep: G = fc_w[0:128]@dec_k packed f16 pairs, [g][u] uint4 layout.
// gy = fc_w[128]@dec_k; gb = fc_b@dec_k + dec_b.
// ---------------------------------------------------------------------------
__global__ __launch_bounds__(256) void k_prep(const float* __restrict__ fc_w,
                                              const float* __restrict__ fc_b,
                                              const float* __restrict__ dec_k,
                                              const float* __restrict__ dec_b,
                                              h2* __restrict__ Gp,
                                              float* __restrict__ gy,
                                              float* __restrict__ gb){
    int blk = blockIdx.x, tid = threadIdx.x;
    int u0 = tid, u1 = tid + 256;
    if (blk < 16){
        float a0[8], a1[8];
        #pragma unroll
        for (int r = 0; r < 8; ++r){ a0[r] = 0.f; a1[r] = 0.f; }
        for (int m = 0; m < 128; ++m){
            float d0 = dec_k[m*G4 + u0], d1 = dec_k[m*G4 + u1];
            #pragma unroll
            for (int r = 0; r < 8; ++r){
                float w = fc_w[(blk*8 + r)*HH + m];
                a0[r] += w * d0; a1[r] += w * d1;
            }
        }
        #pragma unroll
        for (int c = 0; c < 4; ++c){
            Gp[(blk*G4 + u0)*4 + c] = pk(a0[2*c], a0[2*c+1]);
            Gp[(blk*G4 + u1)*4 + c] = pk(a1[2*c], a1[2*c+1]);
        }
    } else if (blk == 16){
        float a0 = 0.f, a1 = 0.f;
        for (int m = 0; m < 128; ++m){
            float w = fc_w[128*HH + m];
            a0 += w * dec_k[m*G4 + u0]; a1 += w * dec_k[m*G4 + u1];
        }
        gy[u0] = a0; gy[u1] = a1;
    } else {
        float a0 = 0.f, a1 = 0.f;
        for (int m = 0; m < 128; ++m){
            float w = fc_b[m];
            a0 += w * dec_k[m*G4 + u0]; a1 += w * dec_k[m*G4 + u1];
        }
        gb[u0] = a0 + dec_b[u0]; gb[u1] = a1 + dec_b[u1];
    }
}

// ---------------------------------------------------------------------------
// k_enc: round-7 verbatim (1024 threads, k-split, 6 barriers/step).
// ---------------------------------------------------------------------------
__global__ __launch_bounds__(1024, 1) void k_enc(const float* __restrict__ inputs,
                                                 const float* __restrict__ enc_k,
                                                 const float* __restrict__ enc_r,
                                                 const float* __restrict__ enc_b,
                                                 const float* __restrict__ ae_w1,
                                                 const float* __restrict__ ae_b1,
                                                 const float* __restrict__ ae_w2,
                                                 float* __restrict__ ws_xenc){
    extern __shared__ float lds[];
    uint4* KLH4 = (uint4*)lds;            // [4][512] uint4 = 8192 floats
    float* XPJT = lds + 8192;             // [128][33] = 4224
    float* XIN  = lds + 12416;            // [96][32]  = 3072
    float* HST  = lds + 15488;            // 256 (h, s fp32 state)
    float* PP   = lds + 15744;            // 1024 partials
    float* PPZ  = lds + 16768;            // 1024 z-halves
    float* PE   = lds + 17792;            // 128
    float* W2E  = lds + 17920;            // 128
    float* AB1E = lds + 18048;            // 128
    h2*    HSP  = (h2*)(lds + 18176);     // 128 h2
    h2*    XTP  = (h2*)(lds + 18240);     // 16 h2
    // total 18256 floats = 73024 B

    const int b = blockIdx.x, tid = threadIdx.x;
    const int u = tid & 511, hf = tid >> 9;
    const int j7 = tid & 127, g8 = tid >> 7;
    const float* xin_g = inputs + b*TT*FF;

    for (int i = tid; i < TT*FF; i += 1024) XIN[i] = xin_g[i];
    for (int i = tid; i < 2048; i += 1024){
        int f8 = i >> 9, uu = i & 511;
        uint4 q;
        q.x = pku(enc_k[(f8*8+0)*G4+uu], enc_k[(f8*8+1)*G4+uu]);
        q.y = pku(enc_k[(f8*8+2)*G4+uu], enc_k[(f8*8+3)*G4+uu]);
        q.z = pku(enc_k[(f8*8+4)*G4+uu], enc_k[(f8*8+5)*G4+uu]);
        q.w = pku(enc_k[(f8*8+6)*G4+uu], enc_k[(f8*8+7)*G4+uu]);
        KLH4[i] = q;
    }
    if (tid < 128){ W2E[tid] = ae_w2[tid]; AB1E[tid] = ae_b1[tid]; HSP[tid] = pk(0.f, 0.f); }
    if (tid < 256) HST[tid] = 0.f;

    h2 rp_e[32], wa_p[16];
    #pragma unroll
    for (int i = 0; i < 32; ++i)
        rp_e[i] = pk(enc_r[(hf*64 + 2*i)*G4 + u], enc_r[(hf*64 + 2*i+1)*G4 + u]);
    #pragma unroll
    for (int i = 0; i < 16; ++i)
        wa_p[i] = pk(ae_w1[(g8*32 + 2*i)*HH + j7], ae_w1[(g8*32 + 2*i+1)*HH + j7]);
    const float eb = (hf == 0) ? enc_b[u] : 0.f;
    __syncthreads();

    {   // XPJT[j][f] = sum_t x[t][f]*ae_w1[(256+t)*128+j]
        int j = tid & 127, fh = tid >> 7;
        float a0=0.f, a1=0.f, a2=0.f, a3=0.f;
        for (int t = 0; t < TT; ++t){
            float w = ae_w1[(256 + t)*HH + j];
            const float* xr = &XIN[t*FF + fh*4];
            a0 += xr[0]*w; a1 += xr[1]*w; a2 += xr[2]*w; a3 += xr[3]*w;
        }
        XPJT[j*33 + fh*4 + 0] = a0;
        XPJT[j*33 + fh*4 + 1] = a1;
        XPJT[j*33 + fh*4 + 2] = a2;
        XPJT[j*33 + fh*4 + 3] = a3;
    }
    __syncthreads();

    const uint4* HSP4 = (const uint4*)HSP;
    const uint4* XTP4 = (const uint4*)XTP;

    for (int t = 0; t < TT; ++t){
        {
            float a0 = 0.f, a1 = 0.f;
            #pragma unroll
            for (int i4 = 0; i4 < 4; ++i4){
                uint4 q = HSP4[g8*4 + i4];
                a0 = fdot2(u2h(q.x), wa_p[i4*4+0], a0);
                a1 = fdot2(u2h(q.y), wa_p[i4*4+1], a1);
                a0 = fdot2(u2h(q.z), wa_p[i4*4+2], a0);
                a1 = fdot2(u2h(q.w), wa_p[i4*4+3], a1);
            }
            PP[tid] = a0 + a1;
        }
        float z = eb;
        {
            float z2 = 0.f;
            #pragma unroll
            for (int i4 = 0; i4 < 8; ++i4){
                uint4 q = HSP4[hf*8 + i4];
                z  = fdot2(u2h(q.x), rp_e[i4*4+0], z);
                z2 = fdot2(u2h(q.y), rp_e[i4*4+1], z2);
                z  = fdot2(u2h(q.z), rp_e[i4*4+2], z);
                z2 = fdot2(u2h(q.w), rp_e[i4*4+3], z2);
            }
            z += z2;
        }
        __syncthreads();
        if (tid < 128){
            float s = AB1E[tid];
            #pragma unroll
            for (int g = 0; g < 8; ++g) s += PP[tid + 128*g];
            PE[tid] = s;
        }
        __syncthreads();
        {
            int f = tid & 31, jg = tid >> 5;
            float acc = 0.f;
            #pragma unroll
            for (int i = 0; i < 4; ++i){
                int j = jg*4 + i;
                acc += ftanh(PE[j] + XPJT[j*33 + f]) * W2E[j];
            }
            PP[tid] = acc;
        }
        __syncthreads();
        if (tid < 32){
            float e = 0.f;
            #pragma unroll
            for (int g = 0; g < 32; ++g) e += PP[g*32 + tid];
            float p = fexp2(e * LOG2E);
            float ss = p;
            #pragma unroll
            for (int d = 16; d; d >>= 1) ss += __shfl_xor(ss, d, 32);
            float xt = p * frcp(ss) * XIN[t*FF + tid];
            float xt2 = __shfl_xor(xt, 1);
            if (!(tid & 1)) XTP[tid >> 1] = pk(xt, xt2);
        }
        __syncthreads();
        {
            float z2 = 0.f;
            #pragma unroll
            for (int c = 0; c < 2; ++c){
                int f8 = hf*2 + c;
                uint4 kq = KLH4[f8*512 + u];
                uint4 xq = XTP4[f8];
                z  = fdot2(u2h(kq.x), u2h(xq.x), z);
                z2 = fdot2(u2h(kq.y), u2h(xq.y), z2);
                z  = fdot2(u2h(kq.z), u2h(xq.z), z);
                z2 = fdot2(u2h(kq.w), u2h(xq.w), z2);
            }
            PPZ[hf*512 + u] = z + z2;
        }
        __syncthreads();
        if (tid < 128){
            int j = tid;
            float zi = PPZ[j]       + PPZ[512 + j];
            float zf = PPZ[128 + j] + PPZ[640 + j];
            float zg = PPZ[256 + j] + PPZ[768 + j];
            float zo = PPZ[384 + j] + PPZ[896 + j];
            float iv = fsigmoid(zi);
            float fv = fsigmoid(zf);
            float gv = ftanh(zg);
            float ov = fsigmoid(zo);
            float cn = fv * HST[128 + j] + iv * gv;
            float hn = ov * ftanh(cn);
            HST[128 + j] = cn;
            HST[j] = hn;
            ws_xenc[(b*TT + t)*HH + j] = hn;
            float hn2 = __shfl_xor(hn, 1);
            float cn2 = __shfl_xor(cn, 1);
            if (!(j & 1)){
                HSP[j >> 1]        = pk(hn, hn2);
                HSP[64 + (j >> 1)] = pk(cn, cn2);
            }
        }
        __syncthreads();
    }
}

// ---------------------------------------------------------------------------
// k_xept: xeptT[b][j][t] = sum_k x_enc[b][t][k] * ad_w1[(256+k)*128 + j]
// ---------------------------------------------------------------------------
__global__ __launch_bounds__(256) void k_xept(const float* __restrict__ ws_xenc,
                                              const float* __restrict__ ad_w1,
                                              float* __restrict__ ws_xept){
    int b = blockIdx.x, q = blockIdx.y, tid = threadIdx.x;
    int j = tid & 127, th = tid >> 7;
    const float* xb = ws_xenc + b*TT*HH;
    float acc[12];
    #pragma unroll
    for (int i = 0; i < 12; ++i) acc[i] = 0.f;
    for (int k = 0; k < 128; ++k){
        float w = ad_w1[(256 + k)*HH + j];
        #pragma unroll
        for (int i = 0; i < 12; ++i){
            int tp = q*24 + th*12 + i;
            acc[i] += xb[tp*HH + k] * w;
        }
    }
    #pragma unroll
    for (int i = 0; i < 12; ++i){
        int tp = q*24 + th*12 + i;
        ws_xept[(b*HH + j)*TT + tp] = acc[i];
    }
}

// ---------------------------------------------------------------------------
// k_dec: round-7 base + two surgical cuts (6 barriers/step, was 8):
//  P1: shuffle att-proj (qA map) writes APJ directly; z-path stays round-7
//      (u=tid&511 -> coalesced G, PPZ combine, gates-as-phase).
//  P2: EP=exp(e) + WS wave partials (no separate softmax phase); ctx phase
//      rebuilds beta from EP broadcasts, normalizes with sum(WS).
// ---------------------------------------------------------------------------
__global__ __launch_bounds__(1024, 1) void k_dec(const float* __restrict__ inputs,
                                                 const float* __restrict__ dec_r,
                                                 const float* __restrict__ ad_w1,
                                                 const float* __restrict__ ad_b1,
                                                 const float* __restrict__ ad_w2,
                                                 const float* __restrict__ ff_w,
                                                 const float* __restrict__ ff_b,
                                                 const h2* __restrict__ Gp,
                                                 const float* __restrict__ gy,
                                                 const float* __restrict__ gb,
                                                 const float* __restrict__ ws_xenc,
                                                 const float* __restrict__ ws_xept,
                                                 float* __restrict__ out){
    extern __shared__ float lds[];
    uint4* XE4 = (uint4*)lds;             // [12][128] uint4 = 6144 floats
    float* XPT = lds + 6144;              // [128][100] = 12800
    float* PP  = lds + 18944;             // 1024
    float* PPZ = lds + 19968;             // 1024
    float* DST = lds + 20992;             // 256: d, c
    float* APJ = lds + 21248;             // 128
    float* CTX = lds + 21376;             // 128
    float* W2L = lds + 21504;             // 128
    h2*    DCP = (h2*)(lds + 21632);      // 128 h2 (64 floats)
    h2*    CXP = (h2*)(lds + 21696);      // 64 h2 (32 floats)
    float* EP  = lds + 21728;             // 128 (96 used): exp(e)
    float* WS  = lds + 21856;             // 16 wave exp-partials
    float* YV  = lds + 21872;             // 96
    // total 21968 floats = 87872 B

    const int b = blockIdx.x, tid = threadIdx.x;
    const int u = tid & 511, hf = tid >> 9;     // z mapping (round-7, coalesced)
    const int jA = tid >> 3, qA = tid & 7;      // attention shuffle mapping

    {   // x_enc -> LDS f16 t-pairs
        const float* xe_g = ws_xenc + b*TT*HH;
        for (int i = tid; i < 12*HH; i += 1024){
            int t8 = i >> 7, k = i & 127;
            uint4 qq;
            qq.x = pku(xe_g[(t8*8 + 0)*HH + k], xe_g[(t8*8 + 1)*HH + k]);
            qq.y = pku(xe_g[(t8*8 + 2)*HH + k], xe_g[(t8*8 + 3)*HH + k]);
            qq.z = pku(xe_g[(t8*8 + 4)*HH + k], xe_g[(t8*8 + 5)*HH + k]);
            qq.w = pku(xe_g[(t8*8 + 6)*HH + k], xe_g[(t8*8 + 7)*HH + k]);
            XE4[i] = qq;
        }
    }
    {   // xept -> LDS, stride 96 -> 100
        const float* src = ws_xept + b*HH*TT + jA*96 + qA*12;
        float* dst = &XPT[jA*100 + qA*12];
        #pragma unroll
        for (int i = 0; i < 12; ++i) dst[i] = src[i];
    }
    if (tid < TT) YV[tid] = inputs[b*TT*FF + tid*FF + (FF-1)];
    if (tid < 128){ W2L[tid] = ad_w2[tid]; DCP[tid] = pk(0.f, 0.f); }
    if (tid < 256) DST[tid] = 0.f;

    h2 rp[32], wp[16];
    #pragma unroll
    for (int i = 0; i < 32; ++i)
        rp[i] = pk(dec_r[(hf*64 + 2*i)*G4 + u], dec_r[(hf*64 + 2*i+1)*G4 + u]);
    #pragma unroll
    for (int i = 0; i < 16; ++i)
        wp[i] = pk(ad_w1[(qA*32 + 2*i)*HH + jA], ad_w1[(qA*32 + 2*i+1)*HH + jA]);
    const float gbr = gb[u], gyr = gy[u];
    const float ab1r = ad_b1[jA];
    __syncthreads();

    const uint4* GQ   = (const uint4*)Gp;
    const uint4* DCP4 = (const uint4*)DCP;
    const uint4* CXP4 = (const uint4*)CXP;

    for (int t = 0; t < TT; ++t){
        // P1: z-partial d@dec_r (u map, broadcasts) + att-proj shuffle -> APJ
        float z = (hf == 0) ? (gbr + YV[t]*gyr) : 0.f;
        {
            float z2 = 0.f;
            #pragma unroll
            for (int i4 = 0; i4 < 8; ++i4){
                uint4 dq = DCP4[hf*8 + i4];
                z  = fdot2(u2h(dq.x), rp[i4*4+0], z);
                z2 = fdot2(u2h(dq.y), rp[i4*4+1], z2);
                z  = fdot2(u2h(dq.z), rp[i4*4+2], z);
                z2 = fdot2(u2h(dq.w), rp[i4*4+3], z2);
            }
            z += z2;
            float a0 = 0.f, a1 = 0.f;
            #pragma unroll
            for (int i4 = 0; i4 < 4; ++i4){
                uint4 dq = DCP4[qA*4 + i4];
                a0 = fdot2(u2h(dq.x), wp[i4*4+0], a0);
                a1 = fdot2(u2h(dq.y), wp[i4*4+1], a1);
                a0 = fdot2(u2h(dq.z), wp[i4*4+2], a0);
                a1 = fdot2(u2h(dq.w), wp[i4*4+3], a1);
            }
            float aa = a0 + a1;
            aa += __shfl_xor(aa, 1);
            aa += __shfl_xor(aa, 2);
            aa += __shfl_xor(aa, 4);
            if (qA == 0) APJ[jA] = aa + ab1r;
        }
        __syncthreads();  // B1
        // P2: e[t'] via 8-lane shuffle -> EP=exp(e), WS wave partials
        {
            int tp = jA;
            float acc = 0.f;
            if (tp < TT){
                #pragma unroll
                for (int jj = 0; jj < 16; ++jj){
                    int jx = qA + 8*jj;
                    acc += ftanh(APJ[jx] + XPT[jx*100 + tp]) * W2L[jx];
                }
            }
            acc += __shfl_xor(acc, 1);
            acc += __shfl_xor(acc, 2);
            acc += __shfl_xor(acc, 4);
            float p = 0.f;
            if (qA == 0 && tp < TT){ p = fexp2(acc * LOG2E); EP[tp] = p; }
            float pw = p;
            pw += __shfl_xor(pw, 8);
            pw += __shfl_xor(pw, 16);
            pw += __shfl_xor(pw, 32);
            if ((tid & 63) == 0) WS[tid >> 6] = pw;
        }
        __syncthreads();  // B2
        // P3: ctx partials, beta rebuilt from EP broadcasts
        {
            int k = tid & 127, th = tid >> 7;
            int t8a = (th < 4) ? th*2 : th + 4;
            int cnt = (th < 4) ? 2 : 1;
            float a = 0.f;
            for (int i = 0; i < cnt; ++i){
                int t8 = t8a + i;
                float4 e0 = *(const float4*)&EP[t8*8];
                float4 e1 = *(const float4*)&EP[t8*8 + 4];
                h2 b0 = pk(e0.x, e0.y), b1 = pk(e0.z, e0.w);
                h2 b2 = pk(e1.x, e1.y), b3 = pk(e1.z, e1.w);
                uint4 xq = XE4[t8*HH + k];
                a = fdot2(u2h(xq.x), b0, a);
                a = fdot2(u2h(xq.y), b1, a);
                a = fdot2(u2h(xq.z), b2, a);
                a = fdot2(u2h(xq.w), b3, a);
            }
            PP[tid] = a;
        }
        __syncthreads();  // B3
        // P4: ctx reduce + normalize (sum WS) + CXP pack
        if (tid < 128){
            float ssum = 0.f;
            #pragma unroll
            for (int w = 0; w < 16; ++w) ssum += WS[w];
            float inv = frcp(ssum);
            float s = 0.f;
            #pragma unroll
            for (int g = 0; g < 8; ++g) s += PP[tid + 128*g];
            float cv = s * inv;
            CTX[tid] = cv;
            float cv2 = __shfl_xor(cv, 1);
            if (!(tid & 1)) CXP[tid >> 1] = pk(cv, cv2);
        }
        __syncthreads();  // B4
        // P5: z += ctx@G (coalesced G stream, broadcast CXP) -> PPZ
        {
            float z2 = 0.f;
            #pragma unroll
            for (int gi = 0; gi < 8; ++gi){
                int g = hf*8 + gi;
                uint4 gq = GQ[g*G4 + u];
                uint4 cc = CXP4[g];
                z  = fdot2(u2h(gq.x), u2h(cc.x), z);
                z2 = fdot2(u2h(gq.y), u2h(cc.y), z2);
                z  = fdot2(u2h(gq.z), u2h(cc.z), z);
                z2 = fdot2(u2h(gq.w), u2h(cc.w), z2);
            }
            PPZ[hf*512 + u] = z + z2;
        }
        __syncthreads();  // B5
        // P6: gates (combine z-halves) + state update
        if (tid < 128){
            int j = tid;
            float zi = PPZ[j]       + PPZ[512 + j];
            float zf = PPZ[128 + j] + PPZ[640 + j];
            float zg = PPZ[256 + j] + PPZ[768 + j];
            float zo = PPZ[384 + j] + PPZ[896 + j];
            float iv = fsigmoid(zi);
            float fv = fsigmoid(zf);
            float gv = ftanh(zg);
            float ov = fsigmoid(zo);
            float cn = fv * DST[128 + j] + iv * gv;
            float hn = ov * ftanh(cn);
            DST[128 + j] = cn;
            DST[j] = hn;
            float hn2 = __shfl_xor(hn, 1);
            float cn2 = __shfl_xor(cn, 1);
            if (!(j & 1)){
                DCP[j >> 1]        = pk(hn, hn2);
                DCP[64 + (j >> 1)] = pk(cn, cn2);
            }
        }
        __syncthreads();  // B6
    }

    // output: y_pred = [d_n, ctx] @ ff_w + ff_b (fp32)
    {
        int jp = tid & 31, sg = tid >> 5;
        float a = 0.f;
        #pragma unroll
        for (int kk = 0; kk < 8; ++kk){
            int k = sg*8 + kk;
            float val = (k < 128) ? DST[k] : CTX[k - 128];
            a += val * ff_w[k*FF + jp];
        }
        PP[sg*32 + jp] = a;
    }
    __syncthreads();
    if (tid < 32){
        float o = ff_b[tid];
        #pragma unroll
        for (int s = 0; s < 32; ++s) o += PP[s*32 + tid];
        out[b*FF + tid] = o;
    }
}

// ---------------------------------------------------------------------------
extern "C" void kernel_launch(void* const* d_in, const int* in_sizes, int n_in,
                              void* d_out, int out_size, void* d_ws, size_t ws_size,
                              hipStream_t stream) {
    const float* inputs = (const float*)d_in[0];
    const float* enc_k  = (const float*)d_in[1];
    const float* enc_r  = (const float*)d_in[2];
    const float* enc_b  = (const float*)d_in[3];
    const float* ae_w1  = (const float*)d_in[4];
    const float* ae_b1  = (const float*)d_in[5];
    const float* ae_w2  = (const float*)d_in[6];
    // d_in[7] = ae_b2 (softmax-invariant, unused)
    const float* dec_k  = (const float*)d_in[8];
    const float* dec_r  = (const float*)d_in[9];
    const float* dec_b  = (const float*)d_in[10];
    const float* ad_w1  = (const float*)d_in[11];
    const float* ad_b1  = (const float*)d_in[12];
    const float* ad_w2  = (const float*)d_in[13];
    // d_in[14] = ad_b2 (softmax-invariant, unused)
    const float* fc_w   = (const float*)d_in[15];
    const float* fc_b   = (const float*)d_in[16];
    const float* ff_w   = (const float*)d_in[17];
    const float* ff_b   = (const float*)d_in[18];

    float* ws      = (float*)d_ws;
    float* ws_xenc = ws;                     // 64*96*128 floats
    float* ws_xept = ws + 786432;            // 64*128*96 floats
    h2*    Gp      = (h2*)(ws + 1572864);    // 32768 h2 (128 KB)
    float* gy      = ws + 1605632;           // 512
    float* gb      = ws + 1606144;           // 512

    hipFuncSetAttribute((const void*)k_enc, hipFuncAttributeMaxDynamicSharedMemorySize, 73024);
    hipFuncSetAttribute((const void*)k_dec, hipFuncAttributeMaxDynamicSharedMemorySize, 87872);

    k_prep<<<18, 256, 0, stream>>>(fc_w, fc_b, dec_k, dec_b, Gp, gy, gb);
    k_enc<<<64, 1024, 73024, stream>>>(inputs, enc_k, enc_r, enc_b, ae_w1, ae_b1, ae_w2, ws_xenc);
    k_xept<<<dim3(64, 4), 256, 0, stream>>>(ws_xenc, ad_w1, ws_xept);
    k_dec<<<64, 1024, 87872, stream>>>(inputs, dec_r, ad_w1, ad_b1, ad_w2, ff_w, ff_b,
                                       Gp, gy, gb, ws_xenc, ws_xept, (float*)d_out);
}

// Round 10
// 838.136 us; speedup vs baseline: 1.4331x; 1.4066x over previous
//
#include <hip/hip_runtime.h>

#define TT 96
#define FF 32
#define HH 128
#define G4 512
#define LOG2E 1.4426950408889634f

typedef _Float16 h2 __attribute__((ext_vector_type(2)));

__device__ __forceinline__ float fexp2(float x){ return __builtin_amdgcn_exp2f(x); }
__device__ __forceinline__ float frcp(float x){ return __builtin_amdgcn_rcpf(x); }
__device__ __forceinline__ float fsigmoid(float x){ return frcp(1.0f + fexp2(-LOG2E*x)); }
__device__ __forceinline__ float ftanh(float x){
    float u = fexp2(2.0f*LOG2E*x);
    return 1.0f - 2.0f*frcp(1.0f + u);
}
__device__ __forceinline__ h2 pk(float a, float b){
    h2 r; r.x = (_Float16)a; r.y = (_Float16)b; return r;
}
__device__ __forceinline__ unsigned pku(float a, float b){
    return __builtin_bit_cast(unsigned, pk(a, b));
}
__device__ __forceinline__ h2 u2h(unsigned v){ return __builtin_bit_cast(h2, v); }
__device__ __forceinline__ float fdot2(h2 a, h2 b, float c){
#if __has_builtin(__builtin_amdgcn_fdot2)
    return __builtin_amdgcn_fdot2(a, b, c, false);
#else
    return c + (float)a.x*(float)b.x + (float)a.y*(float)b.y;
#endif
}

// ---------------------------------------------------------------------------
// k_prep: G = fc_w[0:128]@dec_k packed f16 pairs, [g][u] uint4 layout.
// gy = fc_w[128]@dec_k; gb = fc_b@dec_k + dec_b.
// ---------------------------------------------------------------------------
__global__ __launch_bounds__(256) void k_prep(const float* __restrict__ fc_w,
                                              const float* __restrict__ fc_b,
                                              const float* __restrict__ dec_k,
                                              const float* __restrict__ dec_b,
                                              h2* __restrict__ Gp,
                                              float* __restrict__ gy,
                                              float* __restrict__ gb){
    int blk = blockIdx.x, tid = threadIdx.x;
    int u0 = tid, u1 = tid + 256;
    if (blk < 16){
        float a0[8], a1[8];
        #pragma unroll
        for (int r = 0; r < 8; ++r){ a0[r] = 0.f; a1[r] = 0.f; }
        for (int m = 0; m < 128; ++m){
            float d0 = dec_k[m*G4 + u0], d1 = dec_k[m*G4 + u1];
            #pragma unroll
            for (int r = 0; r < 8; ++r){
                float w = fc_w[(blk*8 + r)*HH + m];
                a0[r] += w * d0; a1[r] += w * d1;
            }
        }
        #pragma unroll
        for (int c = 0; c < 4; ++c){
            Gp[(blk*G4 + u0)*4 + c] = pk(a0[2*c], a0[2*c+1]);
            Gp[(blk*G4 + u1)*4 + c] = pk(a1[2*c], a1[2*c+1]);
        }
    } else if (blk == 16){
        float a0 = 0.f, a1 = 0.f;
        for (int m = 0; m < 128; ++m){
            float w = fc_w[128*HH + m];
            a0 += w * dec_k[m*G4 + u0]; a1 += w * dec_k[m*G4 + u1];
        }
        gy[u0] = a0; gy[u1] = a1;
    } else {
        float a0 = 0.f, a1 = 0.f;
        for (int m = 0; m < 128; ++m){
            float w = fc_b[m];
            a0 += w * dec_k[m*G4 + u0]; a1 += w * dec_k[m*G4 + u1];
        }
        gb[u0] = a0 + dec_b[u0]; gb[u1] = a1 + dec_b[u1];
    }
}

// ---------------------------------------------------------------------------
// k_enc: round-7 structure. Round-10: wa_p weights moved from registers to
// LDS f16 (WAE4) -> per-thread arrays = rp_e[32] only (~55 VGPR, no spill).
// ---------------------------------------------------------------------------
__global__ __launch_bounds__(1024, 1) void k_enc(const float* __restrict__ inputs,
                                                 const float* __restrict__ enc_k,
                                                 const float* __restrict__ enc_r,
                                                 const float* __restrict__ enc_b,
                                                 const float* __restrict__ ae_w1,
                                                 const float* __restrict__ ae_b1,
                                                 const float* __restrict__ ae_w2,
                                                 float* __restrict__ ws_xenc){
    extern __shared__ float lds[];
    uint4* KLH4 = (uint4*)lds;            // [4][512] uint4 = 8192 floats
    float* XPJT = lds + 8192;             // [128][33] = 4224
    float* XIN  = lds + 12416;            // [96][32]  = 3072
    float* HST  = lds + 15488;            // 256 (h, s fp32 state)
    float* PP   = lds + 15744;            // 1024 partials
    float* PPZ  = lds + 16768;            // 1024 z-halves
    float* PE   = lds + 17792;            // 128
    float* W2E  = lds + 17920;            // 128
    float* AB1E = lds + 18048;            // 128
    h2*    HSP  = (h2*)(lds + 18176);     // 128 h2
    h2*    XTP  = (h2*)(lds + 18240);     // 16 h2
    uint4* WAE4 = (uint4*)(lds + 18256);  // [32][128] uint4 = 16384 floats (ae_w1 f16)
    // total 34640 floats = 138560 B

    const int b = blockIdx.x, tid = threadIdx.x;
    const int u = tid & 511, hf = tid >> 9;
    const int j7 = tid & 127, g8 = tid >> 7;
    const float* xin_g = inputs + b*TT*FF;

    for (int i = tid; i < TT*FF; i += 1024) XIN[i] = xin_g[i];
    for (int i = tid; i < 2048; i += 1024){
        int f8 = i >> 9, uu = i & 511;
        uint4 q;
        q.x = pku(enc_k[(f8*8+0)*G4+uu], enc_k[(f8*8+1)*G4+uu]);
        q.y = pku(enc_k[(f8*8+2)*G4+uu], enc_k[(f8*8+3)*G4+uu]);
        q.z = pku(enc_k[(f8*8+4)*G4+uu], enc_k[(f8*8+5)*G4+uu]);
        q.w = pku(enc_k[(f8*8+6)*G4+uu], enc_k[(f8*8+7)*G4+uu]);
        KLH4[i] = q;
    }
    // ae_w1 rows 0..255 -> f16 LDS: WAE4[(g*4+i4)*128+j] packs rows g*32+8*i4 .. +7
    for (int i = tid; i < 4096; i += 1024){
        int j = i & 127, i4g = i >> 7;
        int kbase = (i4g >> 2)*32 + (i4g & 3)*8;
        uint4 wv;
        wv.x = pku(ae_w1[(kbase+0)*HH + j], ae_w1[(kbase+1)*HH + j]);
        wv.y = pku(ae_w1[(kbase+2)*HH + j], ae_w1[(kbase+3)*HH + j]);
        wv.z = pku(ae_w1[(kbase+4)*HH + j], ae_w1[(kbase+5)*HH + j]);
        wv.w = pku(ae_w1[(kbase+6)*HH + j], ae_w1[(kbase+7)*HH + j]);
        WAE4[i] = wv;
    }
    if (tid < 128){ W2E[tid] = ae_w2[tid]; AB1E[tid] = ae_b1[tid]; HSP[tid] = pk(0.f, 0.f); }
    if (tid < 256) HST[tid] = 0.f;

    h2 rp_e[32];
    #pragma unroll
    for (int i = 0; i < 32; ++i)
        rp_e[i] = pk(enc_r[(hf*64 + 2*i)*G4 + u], enc_r[(hf*64 + 2*i+1)*G4 + u]);
    const float eb = (hf == 0) ? enc_b[u] : 0.f;
    __syncthreads();

    {   // XPJT[j][f] = sum_t x[t][f]*ae_w1[(256+t)*128+j]
        int j = tid & 127, fh = tid >> 7;
        float a0=0.f, a1=0.f, a2=0.f, a3=0.f;
        for (int t = 0; t < TT; ++t){
            float w = ae_w1[(256 + t)*HH + j];
            const float* xr = &XIN[t*FF + fh*4];
            a0 += xr[0]*w; a1 += xr[1]*w; a2 += xr[2]*w; a3 += xr[3]*w;
        }
        XPJT[j*33 + fh*4 + 0] = a0;
        XPJT[j*33 + fh*4 + 1] = a1;
        XPJT[j*33 + fh*4 + 2] = a2;
        XPJT[j*33 + fh*4 + 3] = a3;
    }
    __syncthreads();

    const uint4* HSP4 = (const uint4*)HSP;
    const uint4* XTP4 = (const uint4*)XTP;

    for (int t = 0; t < TT; ++t){
        // PH-A: att-proj partials, weights from LDS (b128, lane-stride-16B)
        {
            float a0 = 0.f, a1 = 0.f;
            #pragma unroll
            for (int i4 = 0; i4 < 4; ++i4){
                uint4 q  = HSP4[g8*4 + i4];
                uint4 wv = WAE4[(g8*4 + i4)*128 + j7];
                a0 = fdot2(u2h(q.x), u2h(wv.x), a0);
                a1 = fdot2(u2h(q.y), u2h(wv.y), a1);
                a0 = fdot2(u2h(q.z), u2h(wv.z), a0);
                a1 = fdot2(u2h(q.w), u2h(wv.w), a1);
            }
            PP[tid] = a0 + a1;
        }
        float z = eb;
        {
            float z2 = 0.f;
            #pragma unroll
            for (int i4 = 0; i4 < 8; ++i4){
                uint4 q = HSP4[hf*8 + i4];
                z  = fdot2(u2h(q.x), rp_e[i4*4+0], z);
                z2 = fdot2(u2h(q.y), rp_e[i4*4+1], z2);
                z  = fdot2(u2h(q.z), rp_e[i4*4+2], z);
                z2 = fdot2(u2h(q.w), rp_e[i4*4+3], z2);
            }
            z += z2;
        }
        __syncthreads();
        if (tid < 128){
            float s = AB1E[tid];
            #pragma unroll
            for (int g = 0; g < 8; ++g) s += PP[tid + 128*g];
            PE[tid] = s;
        }
        __syncthreads();
        {
            int f = tid & 31, jg = tid >> 5;
            float acc = 0.f;
            #pragma unroll
            for (int i = 0; i < 4; ++i){
                int j = jg*4 + i;
                acc += ftanh(PE[j] + XPJT[j*33 + f]) * W2E[j];
            }
            PP[tid] = acc;
        }
        __syncthreads();
        if (tid < 32){
            float e = 0.f;
            #pragma unroll
            for (int g = 0; g < 32; ++g) e += PP[g*32 + tid];
            float p = fexp2(e * LOG2E);
            float ss = p;
            #pragma unroll
            for (int d = 16; d; d >>= 1) ss += __shfl_xor(ss, d, 32);
            float xt = p * frcp(ss) * XIN[t*FF + tid];
            float xt2 = __shfl_xor(xt, 1);
            if (!(tid & 1)) XTP[tid >> 1] = pk(xt, xt2);
        }
        __syncthreads();
        {
            float z2 = 0.f;
            #pragma unroll
            for (int c = 0; c < 2; ++c){
                int f8 = hf*2 + c;
                uint4 kq = KLH4[f8*512 + u];
                uint4 xq = XTP4[f8];
                z  = fdot2(u2h(kq.x), u2h(xq.x), z);
                z2 = fdot2(u2h(kq.y), u2h(xq.y), z2);
                z  = fdot2(u2h(kq.z), u2h(xq.z), z);
                z2 = fdot2(u2h(kq.w), u2h(xq.w), z2);
            }
            PPZ[hf*512 + u] = z + z2;
        }
        __syncthreads();
        if (tid < 128){
            int j = tid;
            float zi = PPZ[j]       + PPZ[512 + j];
            float zf = PPZ[128 + j] + PPZ[640 + j];
            float zg = PPZ[256 + j] + PPZ[768 + j];
            float zo = PPZ[384 + j] + PPZ[896 + j];
            float iv = fsigmoid(zi);
            float fv = fsigmoid(zf);
            float gv = ftanh(zg);
            float ov = fsigmoid(zo);
            float cn = fv * HST[128 + j] + iv * gv;
            float hn = ov * ftanh(cn);
            HST[128 + j] = cn;
            HST[j] = hn;
            ws_xenc[(b*TT + t)*HH + j] = hn;
            float hn2 = __shfl_xor(hn, 1);
            float cn2 = __shfl_xor(cn, 1);
            if (!(j & 1)){
                HSP[j >> 1]        = pk(hn, hn2);
                HSP[64 + (j >> 1)] = pk(cn, cn2);
            }
        }
        __syncthreads();
    }
}

// ---------------------------------------------------------------------------
// k_xept: xeptT[b][j][t] = sum_k x_enc[b][t][k] * ad_w1[(256+k)*128 + j]
// ---------------------------------------------------------------------------
__global__ __launch_bounds__(256) void k_xept(const float* __restrict__ ws_xenc,
                                              const float* __restrict__ ad_w1,
                                              float* __restrict__ ws_xept){
    int b = blockIdx.x, q = blockIdx.y, tid = threadIdx.x;
    int j = tid & 127, th = tid >> 7;
    const float* xb = ws_xenc + b*TT*HH;
    float acc[12];
    #pragma unroll
    for (int i = 0; i < 12; ++i) acc[i] = 0.f;
    for (int k = 0; k < 128; ++k){
        float w = ad_w1[(256 + k)*HH + j];
        #pragma unroll
        for (int i = 0; i < 12; ++i){
            int tp = q*24 + th*12 + i;
            acc[i] += xb[tp*HH + k] * w;
        }
    }
    #pragma unroll
    for (int i = 0; i < 12; ++i){
        int tp = q*24 + th*12 + i;
        ws_xept[(b*HH + j)*TT + tp] = acc[i];
    }
}

// ---------------------------------------------------------------------------
// k_dec: round-7 structure (8 barriers/step — known-good 562 µs). Round-10:
// wp weights moved from registers to LDS f16 (WDC4) -> per-thread arrays =
// rp[32] only (~55 VGPR, no spill).
// ---------------------------------------------------------------------------
__global__ __launch_bounds__(1024, 1) void k_dec(const float* __restrict__ inputs,
                                                 const float* __restrict__ dec_r,
                                                 const float* __restrict__ ad_w1,
                                                 const float* __restrict__ ad_b1,
                                                 const float* __restrict__ ad_w2,
                                                 const float* __restrict__ ff_w,
                                                 const float* __restrict__ ff_b,
                                                 const h2* __restrict__ Gp,
                                                 const float* __restrict__ gy,
                                                 const float* __restrict__ gb,
                                                 const float* __restrict__ ws_xenc,
                                                 const float* __restrict__ ws_xept,
                                                 float* __restrict__ out){
    extern __shared__ float lds[];
    uint4* XE4 = (uint4*)lds;             // [12][128] uint4 = 6144 floats
    float* XPT = lds + 6144;              // [128][96] = 12288
    float* PP  = lds + 18432;             // 1024
    float* PPZ = lds + 19456;             // 1024
    float* DST = lds + 20480;             // 256: d, c
    float* APJ = lds + 20736;             // 128
    float* CTX = lds + 20864;             // 128
    float* W2L = lds + 20992;             // 128
    float* SCAL= lds + 21120;             // 8
    h2*    DCP = (h2*)(lds + 21128);      // 128 h2
    h2*    CXP = (h2*)(lds + 21192);      // 64 h2
    h2*    BEP = (h2*)(lds + 21224);      // 64 h2 (48 used)
    float* YV  = lds + 21256;             // 96
    uint4* WDC4= (uint4*)(lds + 21352);   // [32][128] uint4 = 16384 floats (ad_w1 f16)
    // total 37736 floats = 150944 B

    const int b = blockIdx.x, tid = threadIdx.x;
    const int u = tid & 511, hf = tid >> 9;        // unit, k-half
    const int j7 = tid & 127, g8 = tid >> 7;       // attention mapping

    {   // x_enc -> LDS f16 t-pairs
        const float* xe_g = ws_xenc + b*TT*HH;
        for (int i = tid; i < 12*HH; i += 1024){
            int t8 = i >> 7, k = i & 127;
            uint4 qq;
            qq.x = pku(xe_g[(t8*8 + 0)*HH + k], xe_g[(t8*8 + 1)*HH + k]);
            qq.y = pku(xe_g[(t8*8 + 2)*HH + k], xe_g[(t8*8 + 3)*HH + k]);
            qq.z = pku(xe_g[(t8*8 + 4)*HH + k], xe_g[(t8*8 + 5)*HH + k]);
            qq.w = pku(xe_g[(t8*8 + 6)*HH + k], xe_g[(t8*8 + 7)*HH + k]);
            XE4[i] = qq;
        }
    }
    {   // xept -> LDS fp32 (one-time, coalesced)
        const float* xp_g = ws_xept + b*HH*TT;
        for (int i = tid; i < HH*TT; i += 1024) XPT[i] = xp_g[i];
    }
    // ad_w1 rows 0..255 -> f16 LDS: WDC4[(g*4+i4)*128+j] packs rows g*32+8*i4 .. +7
    for (int i = tid; i < 4096; i += 1024){
        int j = i & 127, i4g = i >> 7;
        int kbase = (i4g >> 2)*32 + (i4g & 3)*8;
        uint4 wv;
        wv.x = pku(ad_w1[(kbase+0)*HH + j], ad_w1[(kbase+1)*HH + j]);
        wv.y = pku(ad_w1[(kbase+2)*HH + j], ad_w1[(kbase+3)*HH + j]);
        wv.z = pku(ad_w1[(kbase+4)*HH + j], ad_w1[(kbase+5)*HH + j]);
        wv.w = pku(ad_w1[(kbase+6)*HH + j], ad_w1[(kbase+7)*HH + j]);
        WDC4[i] = wv;
    }
    if (tid < TT) YV[tid] = inputs[b*TT*FF + tid*FF + (FF-1)];
    if (tid < 128){ W2L[tid] = ad_w2[tid]; DCP[tid] = pk(0.f, 0.f); }
    if (tid < 256) DST[tid] = 0.f;

    h2 rp[32];
    #pragma unroll
    for (int i = 0; i < 32; ++i)
        rp[i] = pk(dec_r[(hf*64 + 2*i)*G4 + u], dec_r[(hf*64 + 2*i+1)*G4 + u]);
    const float gbr = gb[u], gyr = gy[u];
    const float ab1 = (tid < 128) ? ad_b1[tid] : 0.f;

    __syncthreads();

    const uint4* GQ   = (const uint4*)Gp;
    const uint4* DCP4 = (const uint4*)DCP;
    const uint4* CXP4 = (const uint4*)CXP;
    const uint4* BEP4 = (const uint4*)BEP;

    for (int t = 0; t < TT; ++t){
        // PH-1: att-proj partials, weights from LDS (b128, lane-stride-16B)
        {
            float a0 = 0.f, a1 = 0.f;
            #pragma unroll
            for (int i4 = 0; i4 < 4; ++i4){
                uint4 q  = DCP4[g8*4 + i4];
                uint4 wv = WDC4[(g8*4 + i4)*128 + j7];
                a0 = fdot2(u2h(q.x), u2h(wv.x), a0);
                a1 = fdot2(u2h(q.y), u2h(wv.y), a1);
                a0 = fdot2(u2h(q.z), u2h(wv.z), a0);
                a1 = fdot2(u2h(q.w), u2h(wv.w), a1);
            }
            PP[tid] = a0 + a1;
        }
        // PH-5a: z-half from d@dec_r
        float z = (hf == 0) ? (gbr + YV[t]*gyr) : 0.f;
        {
            float z2 = 0.f;
            #pragma unroll
            for (int i4 = 0; i4 < 8; ++i4){
                uint4 q = DCP4[hf*8 + i4];
                z  = fdot2(u2h(q.x), rp[i4*4+0], z);
                z2 = fdot2(u2h(q.y), rp[i4*4+1], z2);
                z  = fdot2(u2h(q.z), rp[i4*4+2], z);
                z2 = fdot2(u2h(q.w), rp[i4*4+3], z2);
            }
            z += z2;
        }
        __syncthreads();
        if (tid < 128){
            float s = ab1;
            #pragma unroll
            for (int g = 0; g < 8; ++g) s += PP[tid + 128*g];
            APJ[tid] = s;
        }
        __syncthreads();
        // PH-2: e[t'] partials (8 j-chunks of 16) — xept from LDS
        {
            int tp = tid & 127, jg = tid >> 7;
            float acc = 0.f;
            if (tp < TT){
                const float* xrow = &XPT[(jg*16)*TT + tp];
                #pragma unroll
                for (int q4 = 0; q4 < 4; ++q4){
                    float4 aj = *(const float4*)&APJ[jg*16 + q4*4];
                    float4 wj = *(const float4*)&W2L[jg*16 + q4*4];
                    acc += ftanh(aj.x + xrow[(q4*4+0)*TT]) * wj.x;
                    acc += ftanh(aj.y + xrow[(q4*4+1)*TT]) * wj.y;
                    acc += ftanh(aj.z + xrow[(q4*4+2)*TT]) * wj.z;
                    acc += ftanh(aj.w + xrow[(q4*4+3)*TT]) * wj.w;
                }
            }
            PP[tid] = acc;
        }
        __syncthreads();
        // softmax over 96 on wave 0 (no max-sub); packed beta pairs
        if (tid < 64){
            float ea = 0.f;
            #pragma unroll
            for (int g = 0; g < 8; ++g) ea += PP[tid + 128*g];
            float pa = fexp2(ea * LOG2E);
            float pb = 0.f;
            if (tid < 32){
                float ebv = 0.f;
                #pragma unroll
                for (int g = 0; g < 8; ++g) ebv += PP[64 + tid + 128*g];
                pb = fexp2(ebv * LOG2E);
            }
            float ss = pa + pb;
            #pragma unroll
            for (int d = 32; d; d >>= 1) ss += __shfl_xor(ss, d, 64);
            float pa2 = __shfl_xor(pa, 1);
            float pb2 = __shfl_xor(pb, 1);
            if (!(tid & 1)){
                BEP[tid >> 1] = pk(pa, pa2);
                if (tid < 32) BEP[32 + (tid >> 1)] = pk(pb, pb2);
            }
            if (tid == 0) SCAL[0] = frcp(ss);
        }
        __syncthreads();
        // PH-4: ctx partials
        {
            int k = tid & 127, th = tid >> 7;
            int t8a = (th < 4) ? th*2 : th + 4;
            int cnt = (th < 4) ? 2 : 1;
            float a = 0.f;
            for (int i = 0; i < cnt; ++i){
                int t8 = t8a + i;
                uint4 q  = XE4[t8*HH + k];
                uint4 bb = BEP4[t8];
                a = fdot2(u2h(q.x), u2h(bb.x), a);
                a = fdot2(u2h(q.y), u2h(bb.y), a);
                a = fdot2(u2h(q.z), u2h(bb.z), a);
                a = fdot2(u2h(q.w), u2h(bb.w), a);
            }
            PP[tid] = a;
        }
        __syncthreads();
        if (tid < 128){
            float s = 0.f;
            #pragma unroll
            for (int g = 0; g < 8; ++g) s += PP[tid + 128*g];
            float cv = s * SCAL[0];
            CTX[tid] = cv;
            float cv2 = __shfl_xor(cv, 1);
            if (!(tid & 1)) CXP[tid >> 1] = pk(cv, cv2);
        }
        __syncthreads();
        // PH-5b: z-half += ctx@G (G streamed from L2, groups hf*8..+7)
        {
            float z2 = 0.f;
            #pragma unroll
            for (int gi = 0; gi < 8; ++gi){
                int g = hf*8 + gi;
                uint4 q  = GQ[g*G4 + u];
                uint4 cc = CXP4[g];
                z  = fdot2(u2h(q.x), u2h(cc.x), z);
                z2 = fdot2(u2h(q.y), u2h(cc.y), z2);
                z  = fdot2(u2h(q.z), u2h(cc.z), z);
                z2 = fdot2(u2h(q.w), u2h(cc.w), z2);
            }
            PPZ[hf*512 + u] = z + z2;
        }
        __syncthreads();
        // PH-6: gates (combine z-halves) + packed-state update
        if (tid < 128){
            int j = tid;
            float zi = PPZ[j]       + PPZ[512 + j];
            float zf = PPZ[128 + j] + PPZ[640 + j];
            float zg = PPZ[256 + j] + PPZ[768 + j];
            float zo = PPZ[384 + j] + PPZ[896 + j];
            float iv = fsigmoid(zi);
            float fv = fsigmoid(zf);
            float gv = ftanh(zg);
            float ov = fsigmoid(zo);
            float cn = fv * DST[128 + j] + iv * gv;
            float hn = ov * ftanh(cn);
            DST[128 + j] = cn;
            DST[j] = hn;
            float hn2 = __shfl_xor(hn, 1);
            float cn2 = __shfl_xor(cn, 1);
            if (!(j & 1)){
                DCP[j >> 1]        = pk(hn, hn2);
                DCP[64 + (j >> 1)] = pk(cn, cn2);
            }
        }
        __syncthreads();
    }

    // output: y_pred = [d_n, ctx] @ ff_w + ff_b (fp32)
    {
        int jp = tid & 31, sg = tid >> 5;
        float a = 0.f;
        #pragma unroll
        for (int kk = 0; kk < 8; ++kk){
            int k = sg*8 + kk;
            float val = (k < 128) ? DST[k] : CTX[k - 128];
            a += val * ff_w[k*FF + jp];
        }
        PP[sg*32 + jp] = a;
    }
    __syncthreads();
    if (tid < 32){
        float o = ff_b[tid];
        #pragma unroll
        for (int s = 0; s < 32; ++s) o += PP[s*32 + tid];
        out[b*FF + tid] = o;
    }
}

// ---------------------------------------------------------------------------
extern "C" void kernel_launch(void* const* d_in, const int* in_sizes, int n_in,
                              void* d_out, int out_size, void* d_ws, size_t ws_size,
                              hipStream_t stream) {
    const float* inputs = (const float*)d_in[0];
    const float* enc_k  = (const float*)d_in[1];
    const float* enc_r  = (const float*)d_in[2];
    const float* enc_b  = (const float*)d_in[3];
    const float* ae_w1  = (const float*)d_in[4];
    const float* ae_b1  = (const float*)d_in[5];
    const float* ae_w2  = (const float*)d_in[6];
    // d_in[7] = ae_b2 (softmax-invariant, unused)
    const float* dec_k  = (const float*)d_in[8];
    const float* dec_r  = (const float*)d_in[9];
    const float* dec_b  = (const float*)d_in[10];
    const float* ad_w1  = (const float*)d_in[11];
    const float* ad_b1  = (const float*)d_in[12];
    const float* ad_w2  = (const float*)d_in[13];
    // d_in[14] = ad_b2 (softmax-invariant, unused)
    const float* fc_w   = (const float*)d_in[15];
    const float* fc_b   = (const float*)d_in[16];
    const float* ff_w   = (const float*)d_in[17];
    const float* ff_b   = (const float*)d_in[18];

    float* ws      = (float*)d_ws;
    float* ws_xenc = ws;                     // 64*96*128 floats
    float* ws_xept = ws + 786432;            // 64*128*96 floats
    h2*    Gp      = (h2*)(ws + 1572864);    // 32768 h2 (128 KB)
    float* gy      = ws + 1605632;           // 512
    float* gb      = ws + 1606144;           // 512

    hipFuncSetAttribute((const void*)k_enc, hipFuncAttributeMaxDynamicSharedMemorySize, 138560);
    hipFuncSetAttribute((const void*)k_dec, hipFuncAttributeMaxDynamicSharedMemorySize, 150944);

    k_prep<<<18, 256, 0, stream>>>(fc_w, fc_b, dec_k, dec_b, Gp, gy, gb);
    k_enc<<<64, 1024, 138560, stream>>>(inputs, enc_k, enc_r, enc_b, ae_w1, ae_b1, ae_w2, ws_xenc);
    k_xept<<<dim3(64, 4), 256, 0, stream>>>(ws_xenc, ad_w1, ws_xept);
    k_dec<<<64, 1024, 150944, stream>>>(inputs, dec_r, ad_w1, ad_b1, ad_w2, ff_w, ff_b,
                                        Gp, gy, gb, ws_xenc, ws_xept, (float*)d_out);
}